// Round 13
// baseline (41.384 us; speedup 1.0000x reference)
//
#include <hip/hip_runtime.h>

typedef float f32x2 __attribute__((ext_vector_type(2)));
typedef f32x2 c32;   // [0]=re, [1]=im
typedef _Float16 f16x8 __attribute__((ext_vector_type(8)));
typedef float f32x4 __attribute__((ext_vector_type(4)));

__device__ __forceinline__ c32 mkc(float x, float y) { c32 r; r[0] = x; r[1] = y; return r; }

// complex mul/mad via packed fp32 VOP3P
__device__ __forceinline__ c32 cmul(c32 a, c32 b) {
    c32 r;
    asm("v_pk_mul_f32 %0, %1, %2 op_sel:[0,0] op_sel_hi:[0,1]\n\t"
        "v_pk_fma_f32 %0, %1, %2, %0 op_sel:[1,1,0] op_sel_hi:[1,0,1] neg_lo:[1,0,0]"
        : "=&v"(r) : "v"(a), "v"(b));
    return r;
}
__device__ __forceinline__ c32 cmad(c32 a, c32 b, c32 acc) {
    asm("v_pk_fma_f32 %0, %1, %2, %0 op_sel:[0,0,0] op_sel_hi:[0,1,1]\n\t"
        "v_pk_fma_f32 %0, %1, %2, %0 op_sel:[1,1,0] op_sel_hi:[1,0,1] neg_lo:[1,0,0]"
        : "+v"(acc) : "v"(a), "v"(b));
    return acc;
}

// ---------------- gate-matrix build: lanes 0..19 ---------------------------

__device__ __forceinline__ void mk_u3(float th, float ph, float la, c32 U[2][2]) {
    float ct = __cosf(0.5f * th), st = __sinf(0.5f * th);
    U[0][0] = mkc(ct, 0.f);
    U[0][1] = mkc(-__cosf(la) * st, -__sinf(la) * st);
    U[1][0] = mkc(__cosf(ph) * st, __sinf(ph) * st);
    U[1][1] = mkc(__cosf(ph + la) * ct, __sinf(ph + la) * ct);
}

__device__ __forceinline__ void lmul_kron(const c32 A[2][2], const c32 B[2][2], c32 m[4]) {
    c32 t[4];
#pragma unroll
    for (int r = 0; r < 4; ++r) {
        c32 acc = mkc(0.f, 0.f);
#pragma unroll
        for (int k = 0; k < 4; ++k)
            acc = cmad(cmul(A[r >> 1][k >> 1], B[r & 1][k & 1]), m[k], acc);
        t[r] = acc;
    }
#pragma unroll
    for (int r = 0; r < 4; ++r) m[r] = t[r];
}

__device__ void build_col(const float* __restrict__ w, int t, c32* gml) {
    const int g = t >> 2, c = t & 3;
    const float* p = w + g * 15;
    const int c0 = c >> 1, c1 = c & 1;
    c32 A[2][2], B[2][2], m[4], tmp;

    mk_u3(p[0], p[1], p[2], A);
    mk_u3(p[3], p[4], p[5], B);
#pragma unroll
    for (int r = 0; r < 4; ++r) m[r] = cmul(A[r >> 1][c0], B[r & 1][c1]);
    tmp = m[2]; m[2] = m[3]; m[3] = tmp;                 // CNOT(w0->w1)
    {
        float cc = __cosf(0.5f * p[6]), s = __sinf(0.5f * p[6]);
        A[0][0] = mkc(cc, 0.f); A[0][1] = mkc(-s, 0.f);
        A[1][0] = mkc(s, 0.f);  A[1][1] = mkc(cc, 0.f);
        float cz = __cosf(0.5f * p[7]), sz = __sinf(0.5f * p[7]);
        B[0][0] = mkc(cz, -sz); B[0][1] = mkc(0.f, 0.f);
        B[1][0] = mkc(0.f, 0.f); B[1][1] = mkc(cz, sz);
        lmul_kron(A, B, m);
    }
    tmp = m[1]; m[1] = m[3]; m[3] = tmp;                 // CNOT(w1->w0)
    {
        float cc = __cosf(0.5f * p[8]), s = __sinf(0.5f * p[8]);
        A[0][0] = mkc(cc, 0.f); A[0][1] = mkc(-s, 0.f);
        A[1][0] = mkc(s, 0.f);  A[1][1] = mkc(cc, 0.f);
        B[0][0] = mkc(1.f, 0.f); B[0][1] = mkc(0.f, 0.f);
        B[1][0] = mkc(0.f, 0.f); B[1][1] = mkc(1.f, 0.f);
        lmul_kron(A, B, m);
    }
    tmp = m[2]; m[2] = m[3]; m[3] = tmp;                 // CNOT(w0->w1)
    mk_u3(p[9], p[10], p[11], A);
    mk_u3(p[12], p[13], p[14], B);
    lmul_kron(A, B, m);
#pragma unroll
    for (int r = 0; r < 4; ++r) gml[g * 16 + r * 4 + c] = m[r];
}

// ---------------- basis-state simulator (builds U) -------------------------
// Same verified machinery as the R12 batch sim; input = basis vectors.

#define STRIDE 260

__device__ __forceinline__ int swz8(int i) { return i ^ (i >> 4); }
__host__ __device__ constexpr int cswz8(int i) { return i ^ (i >> 4); }

template<int P3, int P2, int P1, int P0>
struct BitMap {
    __device__ static int scatterDyn(int v) {
        return (((v >> 3) & 1) << P3) | (((v >> 2) & 1) << P2) |
               (((v >> 1) & 1) << P1) | ((v & 1) << P0);
    }
    static constexpr int scatter(int v) {
        return (((v >> 3) & 1) << P3) | (((v >> 2) & 1) << P2) |
               (((v >> 1) & 1) << P1) | ((v & 1) << P0);
    }
};

using WA = BitMap<7, 6, 5, 4>;  using LA = BitMap<3, 2, 1, 0>;
using WB = BitMap<3, 2, 1, 0>;  using LB = BitMap<7, 6, 5, 4>;
using WC = BitMap<7, 4, 3, 0>;  using LC = BitMap<6, 5, 2, 1>;
using WD = BitMap<7, 5, 3, 1>;  using LD = BitMap<6, 4, 2, 0>;

template<class WO, class LO, class WN, class LN>
__device__ __forceinline__ void transition2(c32* slA, c32* slB, int c,
                                            c32 sA[16], c32 sB[16]) {
    const int uo = swz8(LO::scatterDyn(c));
#pragma unroll
    for (int r = 0; r < 16; ++r) slA[uo ^ cswz8(WO::scatter(r))] = sA[r];
#pragma unroll
    for (int r = 0; r < 16; ++r) slB[uo ^ cswz8(WO::scatter(r))] = sB[r];
    const int un = swz8(LN::scatterDyn(c));
#pragma unroll
    for (int r = 0; r < 16; ++r) sA[r] = slA[un ^ cswz8(WN::scatter(r))];
#pragma unroll
    for (int r = 0; r < 16; ++r) sB[r] = slB[un ^ cswz8(WN::scatter(r))];
}

constexpr int freePos(int A, int B, int k) {
    int cnt = 0;
    for (int p = 0; p < 4; ++p)
        if (p != A && p != B) { if (cnt == k) return p; ++cnt; }
    return -1;
}

template<int A, int B>
__device__ __forceinline__ void gate(const c32 m[16], c32 s[16]) {
    constexpr int C0 = freePos(A, B, 0);
    constexpr int C1 = freePos(A, B, 1);
#pragma unroll
    for (int q = 0; q < 4; ++q) {
        const int base = ((q & 1) << C0) | (((q >> 1) & 1) << C1);
        const int i00 = base, i01 = base | (1 << B), i10 = base | (1 << A),
                  i11 = base | (1 << A) | (1 << B);
        c32 a0 = s[i00], a1 = s[i01], a2 = s[i10], a3 = s[i11];
        c32 r0 = cmul(m[0],  a0); r0 = cmad(m[1],  a1, r0); r0 = cmad(m[2],  a2, r0); r0 = cmad(m[3],  a3, r0);
        c32 r1 = cmul(m[4],  a0); r1 = cmad(m[5],  a1, r1); r1 = cmad(m[6],  a2, r1); r1 = cmad(m[7],  a3, r1);
        c32 r2 = cmul(m[8],  a0); r2 = cmad(m[9],  a1, r2); r2 = cmad(m[10], a2, r2); r2 = cmad(m[11], a3, r2);
        c32 r3 = cmul(m[12], a0); r3 = cmad(m[13], a1, r3); r3 = cmad(m[14], a2, r3); r3 = cmad(m[15], a3, r3);
        s[i00] = r0; s[i01] = r1; s[i10] = r2; s[i11] = r3;
    }
}

template<int A, int B>
__device__ __forceinline__ void gate2(const c32 m[16], c32 sA[16], c32 sB[16]) {
    gate<A, B>(m, sA);
    gate<A, B>(m, sB);
}

__device__ __forceinline__ void loadm(const c32* gml, int idx, c32 m[16]) {
#pragma unroll
    for (int k = 0; k < 16; ++k) m[k] = gml[idx * 16 + k];
}

// 32 blocks x 64 threads: simulate 256 basis states, emit U as fp16 [512][256]
__global__ __launch_bounds__(64, 1) void basis_kernel(const float* __restrict__ w,
                                                      _Float16* __restrict__ U16) {
    __shared__ c32 TR[8 * STRIDE];
    __shared__ c32 GML[80];
    const int lane = threadIdx.x;
    const int st   = lane >> 4;
    const int c    = lane & 15;
    const int jA   = blockIdx.x * 8 + st;
    const int jB   = jA + 4;

    if (lane < 20) build_col(w, lane, GML);

    // basis states in layout A (i = r*16 + c)
    c32 sA[16], sB[16];
#pragma unroll
    for (int r = 0; r < 16; ++r) {
        sA[r] = mkc((r == (jA >> 4) && c == (jA & 15)) ? 1.f : 0.f, 0.f);
        sB[r] = mkc((r == (jB >> 4) && c == (jB & 15)) ? 1.f : 0.f, 0.f);
    }

    c32* slA = TR + st * STRIDE;
    c32* slB = TR + (st + 4) * STRIDE;
    c32 m[16];

#pragma unroll 1
    for (int pass = 0; pass < 2; ++pass) {
        loadm(GML, pass, m);
        gate2<3, 2>(m, sA, sB); gate2<1, 0>(m, sA, sB); gate2<2, 1>(m, sA, sB);
        transition2<WA, LA, WB, LB>(slA, slB, c, sA, sB);
        gate2<3, 2>(m, sA, sB); gate2<1, 0>(m, sA, sB); gate2<2, 1>(m, sA, sB);
        transition2<WB, LB, WC, LC>(slA, slB, c, sA, sB);
        gate2<2, 1>(m, sA, sB); gate2<0, 3>(m, sA, sB);
        if (pass == 0) transition2<WC, LC, WA, LA>(slA, slB, c, sA, sB);
        else           transition2<WC, LC, WD, LD>(slA, slB, c, sA, sB);
    }
#pragma unroll 1
    for (int pp = 0; pp < 2; ++pp) {
        loadm(GML, 2 + pp, m);
        gate2<2, 1>(m, sA, sB); gate2<0, 3>(m, sA, sB);
        gate2<3, 2>(m, sA, sB); gate2<1, 0>(m, sA, sB);
    }
    loadm(GML, 4, m);
    gate2<2, 0>(m, sA, sB);

    // window D: global amp index i = WD.scatter(r) | LD.scatter(c)
#pragma unroll
    for (int r = 0; r < 16; ++r) {
        const int i = WD::scatter(r) | LD::scatterDyn(c);
        U16[(size_t)i * 256 + jA]         = (_Float16)sA[r][0];
        U16[(size_t)(i + 256) * 256 + jA] = (_Float16)sA[r][1];
        U16[(size_t)i * 256 + jB]         = (_Float16)sB[r][0];
        U16[(size_t)(i + 256) * 256 + jB] = (_Float16)sB[r][1];
    }
}

// ---------------- batch GEMM + expectation epilogue ------------------------
// C[512][32] = U16[512][256] x Xtile^T[256][32], MFMA f32_16x16x32_f16.
// Wave w owns m-tiles t with (t>>2)&3 == w  ->  orbit-closed under
// bit5 (tile^2) and re/im (tile+16): epilogue is register-local.

__global__ __launch_bounds__(256) void gemm_expect_kernel(const float* __restrict__ x,
                                                          const _Float16* __restrict__ U16,
                                                          float* __restrict__ out) {
    __shared__ _Float16 Bl[32][264];   // [state][k] fp16, padded
    __shared__ float nn[32];
    __shared__ float red[4][2][16][9];
    const int tid = threadIdx.x;
    const int wave = tid >> 6, lane = tid & 63;
    const int bs = blockIdx.x * 32;

    // ---- stage X tile -> fp16 LDS [n][k]; per-state squared norms ----
    {
        const int n = tid >> 3, sub = tid & 7;
        const float4* xr = reinterpret_cast<const float4*>(x + (size_t)(bs + n) * 256 + sub * 32);
        float ssq = 0.f;
#pragma unroll
        for (int q = 0; q < 8; ++q) {
            float4 v = xr[q];
            ssq = fmaf(v.x, v.x, fmaf(v.y, v.y, fmaf(v.z, v.z, fmaf(v.w, v.w, ssq))));
            const int k0 = sub * 32 + q * 4;
            Bl[n][k0 + 0] = (_Float16)v.x;
            Bl[n][k0 + 1] = (_Float16)v.y;
            Bl[n][k0 + 2] = (_Float16)v.z;
            Bl[n][k0 + 3] = (_Float16)v.w;
        }
#pragma unroll
        for (int o = 4; o; o >>= 1) ssq += __shfl_xor(ssq, o, 64);
        if (sub == 0) nn[n] = ssq;
    }
    __syncthreads();

    // ---- MFMA main loop ----
    f32x4 acc[2][4][2];
#pragma unroll
    for (int ri = 0; ri < 2; ++ri)
#pragma unroll
        for (int a = 0; a < 4; ++a)
#pragma unroll
            for (int nt = 0; nt < 2; ++nt) acc[ri][a][nt] = (f32x4){0.f, 0.f, 0.f, 0.f};

    const int ml = lane & 15, g = lane >> 4;
    const _Float16* Abase[2][4];
#pragma unroll
    for (int ri = 0; ri < 2; ++ri)
#pragma unroll
        for (int a = 0; a < 4; ++a)
            Abase[ri][a] = U16 + (size_t)(64 * wave + 16 * a + 256 * ri + ml) * 256 + g * 8;

#pragma unroll
    for (int kt = 0; kt < 8; ++kt) {
        f16x8 bf[2];
#pragma unroll
        for (int nt = 0; nt < 2; ++nt)
            bf[nt] = *reinterpret_cast<const f16x8*>(&Bl[nt * 16 + ml][kt * 32 + g * 8]);
#pragma unroll
        for (int ri = 0; ri < 2; ++ri)
#pragma unroll
            for (int a = 0; a < 4; ++a) {
                f16x8 af = *reinterpret_cast<const f16x8*>(Abase[ri][a] + kt * 32);
#pragma unroll
                for (int nt = 0; nt < 2; ++nt)
                    acc[ri][a][nt] = __builtin_amdgcn_mfma_f32_16x16x32_f16(af, bf[nt], acc[ri][a][nt], 0, 0, 0);
            }
    }

    // ---- register-local expectations ----
    // amp index i = 64*wave + 16*a + 4*g + r ; re = acc[0], im = acc[1]
    // qubit2 <-> bit5 = a&2 ; qubit6 <-> bit1 = r&2
#pragma unroll
    for (int nt = 0; nt < 2; ++nt) {
        float E[9];
#pragma unroll
        for (int m = 0; m < 9; ++m) E[m] = 0.f;
#pragma unroll
        for (int a = 0; a < 4; ++a) {
#pragma unroll
            for (int r = 0; r < 4; ++r) {
                float re = acc[0][a][nt][r], im = acc[1][a][nt][r];
                float pr = re * re + im * im;
                E[2] += (a & 2) ? -pr : pr;
                E[5] += (r & 2) ? -pr : pr;
                E[8] += ((a ^ r) & 2) ? -pr : pr;
                if (a < 2) {
                    float pre = acc[0][a + 2][nt][r], pim = acc[1][a + 2][nt][r];
                    E[0] += 2.f * (re * pre + im * pim);
                    E[1] += 2.f * (re * pim - im * pre);
                    float dre = acc[0][a + 2][nt][r ^ 2], dim = acc[1][a + 2][nt][r ^ 2];
                    float dr = re * dre + im * dim;
                    E[6] += 2.f * dr;
                    E[7] += (r & 2) ? 2.f * dr : -2.f * dr;
                }
                if (!(r & 2)) {
                    float qre = acc[0][a][nt][r + 2], qim = acc[1][a][nt][r + 2];
                    E[3] += 2.f * (re * qre + im * qim);
                    E[4] += 2.f * (re * qim - im * qre);
                }
            }
        }
#pragma unroll
        for (int m = 0; m < 9; ++m) {
            E[m] += __shfl_xor(E[m], 16, 64);
            E[m] += __shfl_xor(E[m], 32, 64);
            if (lane < 16) red[wave][nt][lane][m] = E[m];
        }
    }
    __syncthreads();

    if (tid < 32) {
        const int nt = tid >> 4, nc = tid & 15;
        const float innv = 1.0f / nn[tid];
#pragma unroll
        for (int m = 0; m < 9; ++m) {
            float e = red[0][nt][nc][m] + red[1][nt][nc][m] +
                      red[2][nt][nc][m] + red[3][nt][nc][m];
            out[(size_t)(bs + tid) * 9 + m] = e * innv;
        }
    }
}

extern "C" void kernel_launch(void* const* d_in, const int* in_sizes, int n_in,
                              void* d_out, int out_size, void* d_ws, size_t ws_size,
                              hipStream_t stream) {
    const float* x = (const float*)d_in[0];
    const float* w = (const float*)d_in[1];
    float* out = (float*)d_out;
    _Float16* U16 = (_Float16*)d_ws;    // 512*256 fp16 = 256 KB

    // 1) build U by simulating the 256 basis states (verified gate path)
    hipLaunchKernelGGL(basis_kernel, dim3(32), dim3(64), 0, stream, w, U16);

    // 2) batch GEMM (MFMA fp16) + expectation epilogue
    const int batch = in_sizes[0] / 256;     // 8192
    const int nblocks = batch / 32;          // 32 states per block
    hipLaunchKernelGGL(gemm_expect_kernel, dim3(nblocks), dim3(256), 0, stream, x, U16, out);
}

// Round 14
// 28.318 us; speedup vs baseline: 1.4614x; 1.4614x over previous
//
#include <hip/hip_runtime.h>

typedef float f32x2 __attribute__((ext_vector_type(2)));
typedef f32x2 c32;   // [0]=re, [1]=im

__device__ __forceinline__ c32 mkc(float x, float y) { c32 r; r[0] = x; r[1] = y; return r; }

// ---- packed complex helpers (build path: 2-instr tied forms, low volume) --
__device__ __forceinline__ c32 cmul(c32 a, c32 b) {
    c32 r;
    asm("v_pk_mul_f32 %0, %1, %2 op_sel:[0,0] op_sel_hi:[0,1]\n\t"
        "v_pk_fma_f32 %0, %1, %2, %0 op_sel:[1,1,0] op_sel_hi:[1,0,1] neg_lo:[1,0,0]"
        : "=&v"(r) : "v"(a), "v"(b));
    return r;
}
__device__ __forceinline__ c32 cmad(c32 a, c32 b, c32 acc) {
    asm("v_pk_fma_f32 %0, %1, %2, %0 op_sel:[0,0,0] op_sel_hi:[0,1,1]\n\t"
        "v_pk_fma_f32 %0, %1, %2, %0 op_sel:[1,1,0] op_sel_hi:[1,0,1] neg_lo:[1,0,0]"
        : "+v"(acc) : "v"(a), "v"(b));
    return acc;
}

// ---- split-accumulator forms: ONE instruction per op, no intra-block dep --
// P-stream: (m.x*a.x, m.x*a.y)   M-stream: (m.y*a.y, m.y*a.x)
// out = (P.lo - M.lo, P.hi + M.hi)
__device__ __forceinline__ c32 pk_mul_P(c32 m, c32 a) {
    c32 r;
    asm("v_pk_mul_f32 %0, %1, %2 op_sel:[0,0] op_sel_hi:[0,1]"
        : "=v"(r) : "v"(m), "v"(a));
    return r;
}
__device__ __forceinline__ c32 pk_mul_M(c32 m, c32 a) {
    c32 r;
    asm("v_pk_mul_f32 %0, %1, %2 op_sel:[1,1] op_sel_hi:[1,0]"
        : "=v"(r) : "v"(m), "v"(a));
    return r;
}
__device__ __forceinline__ c32 pk_fma_P(c32 m, c32 a, c32 acc) {
    asm("v_pk_fma_f32 %0, %1, %2, %0 op_sel:[0,0,0] op_sel_hi:[0,1,1]"
        : "+v"(acc) : "v"(m), "v"(a));
    return acc;
}
__device__ __forceinline__ c32 pk_fma_M(c32 m, c32 a, c32 acc) {
    asm("v_pk_fma_f32 %0, %1, %2, %0 op_sel:[1,1,0] op_sel_hi:[1,0,1]"
        : "+v"(acc) : "v"(m), "v"(a));
    return acc;
}
__device__ __forceinline__ c32 pk_combine(c32 P, c32 M) {
    c32 r;
    asm("v_pk_add_f32 %0, %1, %2 op_sel:[0,0] op_sel_hi:[1,1] neg_lo:[0,1]"
        : "=v"(r) : "v"(P), "v"(M));
    return r;
}

// ---------------- gate-matrix build: lanes 0..19 ---------------------------

__device__ __forceinline__ void mk_u3(float th, float ph, float la, c32 U[2][2]) {
    float ct = __cosf(0.5f * th), st = __sinf(0.5f * th);
    U[0][0] = mkc(ct, 0.f);
    U[0][1] = mkc(-__cosf(la) * st, -__sinf(la) * st);
    U[1][0] = mkc(__cosf(ph) * st, __sinf(ph) * st);
    U[1][1] = mkc(__cosf(ph + la) * ct, __sinf(ph + la) * ct);
}

__device__ __forceinline__ void lmul_kron(const c32 A[2][2], const c32 B[2][2], c32 m[4]) {
    c32 t[4];
#pragma unroll
    for (int r = 0; r < 4; ++r) {
        c32 acc = mkc(0.f, 0.f);
#pragma unroll
        for (int k = 0; k < 4; ++k)
            acc = cmad(cmul(A[r >> 1][k >> 1], B[r & 1][k & 1]), m[k], acc);
        t[r] = acc;
    }
#pragma unroll
    for (int r = 0; r < 4; ++r) m[r] = t[r];
}

__device__ void build_col(const float* __restrict__ w, int t, c32* gml) {
    const int g = t >> 2, c = t & 3;
    const float* p = w + g * 15;
    const int c0 = c >> 1, c1 = c & 1;
    c32 A[2][2], B[2][2], m[4], tmp;

    mk_u3(p[0], p[1], p[2], A);
    mk_u3(p[3], p[4], p[5], B);
#pragma unroll
    for (int r = 0; r < 4; ++r) m[r] = cmul(A[r >> 1][c0], B[r & 1][c1]);
    tmp = m[2]; m[2] = m[3]; m[3] = tmp;                 // CNOT(w0->w1)
    {
        float cc = __cosf(0.5f * p[6]), s = __sinf(0.5f * p[6]);
        A[0][0] = mkc(cc, 0.f); A[0][1] = mkc(-s, 0.f);
        A[1][0] = mkc(s, 0.f);  A[1][1] = mkc(cc, 0.f);
        float cz = __cosf(0.5f * p[7]), sz = __sinf(0.5f * p[7]);
        B[0][0] = mkc(cz, -sz); B[0][1] = mkc(0.f, 0.f);
        B[1][0] = mkc(0.f, 0.f); B[1][1] = mkc(cz, sz);
        lmul_kron(A, B, m);
    }
    tmp = m[1]; m[1] = m[3]; m[3] = tmp;                 // CNOT(w1->w0)
    {
        float cc = __cosf(0.5f * p[8]), s = __sinf(0.5f * p[8]);
        A[0][0] = mkc(cc, 0.f); A[0][1] = mkc(-s, 0.f);
        A[1][0] = mkc(s, 0.f);  A[1][1] = mkc(cc, 0.f);
        B[0][0] = mkc(1.f, 0.f); B[0][1] = mkc(0.f, 0.f);
        B[1][0] = mkc(0.f, 0.f); B[1][1] = mkc(1.f, 0.f);
        lmul_kron(A, B, m);
    }
    tmp = m[2]; m[2] = m[3]; m[3] = tmp;                 // CNOT(w0->w1)
    mk_u3(p[9], p[10], p[11], A);
    mk_u3(p[12], p[13], p[14], B);
    lmul_kron(A, B, m);
#pragma unroll
    for (int r = 0; r < 4; ++r) gml[g * 16 + r * 4 + c] = m[r];
}

// ---------------- simulator: 2 states per lane, 8 states per wave ---------

#define STRIDE 260

__device__ __forceinline__ int swz8(int i) { return i ^ (i >> 4); }
__host__ __device__ constexpr int cswz8(int i) { return i ^ (i >> 4); }

template<int P3, int P2, int P1, int P0>
struct BitMap {
    __device__ static int scatterDyn(int v) {
        return (((v >> 3) & 1) << P3) | (((v >> 2) & 1) << P2) |
               (((v >> 1) & 1) << P1) | ((v & 1) << P0);
    }
    static constexpr int scatter(int v) {
        return (((v >> 3) & 1) << P3) | (((v >> 2) & 1) << P2) |
               (((v >> 1) & 1) << P1) | ((v & 1) << P0);
    }
};

using WA = BitMap<7, 6, 5, 4>;  using LA = BitMap<3, 2, 1, 0>;
using WB = BitMap<3, 2, 1, 0>;  using LB = BitMap<7, 6, 5, 4>;
using WC = BitMap<7, 4, 3, 0>;  using LC = BitMap<6, 5, 2, 1>;
using WD = BitMap<7, 5, 3, 1>;  using LD = BitMap<6, 4, 2, 0>;

template<class WO, class LO, class WN, class LN>
__device__ __forceinline__ void transition2(c32* slA, c32* slB, int c,
                                            c32 sA[16], c32 sB[16]) {
    const int uo = swz8(LO::scatterDyn(c));
#pragma unroll
    for (int r = 0; r < 16; ++r) slA[uo ^ cswz8(WO::scatter(r))] = sA[r];
#pragma unroll
    for (int r = 0; r < 16; ++r) slB[uo ^ cswz8(WO::scatter(r))] = sB[r];
    const int un = swz8(LN::scatterDyn(c));
#pragma unroll
    for (int r = 0; r < 16; ++r) sA[r] = slA[un ^ cswz8(WN::scatter(r))];
#pragma unroll
    for (int r = 0; r < 16; ++r) sB[r] = slB[un ^ cswz8(WN::scatter(r))];
}

constexpr int freePos(int A, int B, int k) {
    int cnt = 0;
    for (int p = 0; p < 4; ++p)
        if (p != A && p != B) { if (cnt == k) return p; ++cnt; }
    return -1;
}

// dual-state 4x4 gate, split-accumulator, k-outermost round-robin:
// 16 independent P/M chain pairs per quad, dependent ops >=32 instrs apart.
template<int A, int B>
__device__ __forceinline__ void gate2(const c32 m[16], c32 sA[16], c32 sB[16]) {
    constexpr int C0 = freePos(A, B, 0);
    constexpr int C1 = freePos(A, B, 1);
#pragma unroll
    for (int q = 0; q < 4; ++q) {
        const int base = ((q & 1) << C0) | (((q >> 1) & 1) << C1);
        const int idx0 = base;
        const int idx1 = base | (1 << B);
        const int idx2 = base | (1 << A);
        const int idx3 = base | (1 << A) | (1 << B);
        const int idx[4] = {idx0, idx1, idx2, idx3};
        c32 P[2][4], M[2][4];
#pragma unroll
        for (int k = 0; k < 4; ++k) {
#pragma unroll
            for (int st = 0; st < 2; ++st) {
                const c32* s = st ? sB : sA;
                const c32 a = s[idx[k]];
#pragma unroll
                for (int r = 0; r < 4; ++r) {
                    if (k == 0) {
                        P[st][r] = pk_mul_P(m[4 * r], a);
                        M[st][r] = pk_mul_M(m[4 * r], a);
                    } else {
                        P[st][r] = pk_fma_P(m[4 * r + k], a, P[st][r]);
                        M[st][r] = pk_fma_M(m[4 * r + k], a, M[st][r]);
                    }
                }
            }
        }
#pragma unroll
        for (int st = 0; st < 2; ++st) {
            c32* s = st ? sB : sA;
#pragma unroll
            for (int r = 0; r < 4; ++r) s[idx[r]] = pk_combine(P[st][r], M[st][r]);
        }
    }
}

__device__ __forceinline__ void loadm(const c32* gml, int idx, c32 m[16]) {
#pragma unroll
    for (int k = 0; k < 16; ++k) m[k] = gml[idx * 16 + k];
}

// epilogue for one state (window D: qubit2 = reg-bit 2, qubit6 = reg-bit 0)
__device__ __forceinline__ void epilogue(const c32 s[16], int c, int b,
                                         float* __restrict__ out) {
    float e0 = 0, e1 = 0, e2 = 0, e3 = 0, e4 = 0, e5 = 0, e6 = 0, e7 = 0, e8 = 0;
#pragma unroll
    for (int q = 0; q < 4; ++q) {
        const int f = ((q & 1) << 1) | ((q & 2) << 2);
        c32 a00 = s[f], a01 = s[f | 1], a10 = s[f | 4], a11 = s[f | 5];
        float n00 = a00[0] * a00[0] + a00[1] * a00[1];
        float n01 = a01[0] * a01[0] + a01[1] * a01[1];
        float n10 = a10[0] * a10[0] + a10[1] * a10[1];
        float n11 = a11[0] * a11[0] + a11[1] * a11[1];
        float z2r = a00[0] * a10[0] + a00[1] * a10[1] + a01[0] * a11[0] + a01[1] * a11[1];
        float z2i = a00[0] * a10[1] - a00[1] * a10[0] + a01[0] * a11[1] - a01[1] * a11[0];
        float z6r = a00[0] * a01[0] + a00[1] * a01[1] + a10[0] * a11[0] + a10[1] * a11[1];
        float z6i = a00[0] * a01[1] - a00[1] * a01[0] + a10[0] * a11[1] - a10[1] * a11[0];
        float w1r = a00[0] * a11[0] + a00[1] * a11[1];
        float w2r = a01[0] * a10[0] + a01[1] * a10[1];
        e0 += 2.f * z2r;  e1 += 2.f * z2i;  e2 += n00 + n01 - n10 - n11;
        e3 += 2.f * z6r;  e4 += 2.f * z6i;  e5 += n00 - n01 + n10 - n11;
        e6 += 2.f * (w1r + w2r);  e7 += 2.f * (w2r - w1r);
        e8 += n00 - n01 - n10 + n11;
    }
    float e[9] = {e0, e1, e2, e3, e4, e5, e6, e7, e8};
#pragma unroll
    for (int mm = 0; mm < 9; ++mm) {
        float vv = e[mm];
#pragma unroll
        for (int o = 8; o; o >>= 1) vv += __shfl_xor(vv, o, 64);
        e[mm] = vv;
    }
    if (c == 0) {
#pragma unroll
        for (int mm = 0; mm < 9; ++mm) out[b * 9 + mm] = e[mm];
    }
}

__global__ __launch_bounds__(64, 1) void sim_kernel(const float* __restrict__ x,
                                                    const float* __restrict__ w,
                                                    float* __restrict__ out) {
    __shared__ c32 TR[8 * STRIDE];
    __shared__ c32 GML[80];
    const int lane = threadIdx.x;      // one wave per block
    const int st   = lane >> 4;        // slot within wave (0..3)
    const int c    = lane & 15;        // 16 lanes per state
    const int bA   = blockIdx.x * 8 + st;
    const int bB   = bA + 4;

    // issue both states' x loads first; matrix build overlaps the latency
    const float* xbA = x + (size_t)bA * 256 + c;
    const float* xbB = x + (size_t)bB * 256 + c;
    float vA[16], vB[16];
#pragma unroll
    for (int r = 0; r < 16; ++r) vA[r] = xbA[r << 4];
#pragma unroll
    for (int r = 0; r < 16; ++r) vB[r] = xbB[r << 4];

    if (lane < 20) build_col(w, lane, GML);

    float ssA = 0.f, ssB = 0.f;
#pragma unroll
    for (int r = 0; r < 16; ++r) { ssA = fmaf(vA[r], vA[r], ssA); ssB = fmaf(vB[r], vB[r], ssB); }
#pragma unroll
    for (int o = 8; o; o >>= 1) { ssA += __shfl_xor(ssA, o, 64); ssB += __shfl_xor(ssB, o, 64); }
    const float invA = 1.0f / sqrtf(ssA);
    const float invB = 1.0f / sqrtf(ssB);
    c32 sA[16], sB[16];
#pragma unroll
    for (int r = 0; r < 16; ++r) { sA[r] = mkc(vA[r] * invA, 0.f); sB[r] = mkc(vB[r] * invB, 0.f); }

    c32* slA = TR + st * STRIDE;
    c32* slB = TR + (st + 4) * STRIDE;
    c32 m[16];

    // ---- LAYER1 x2 (rolled) ----------------------------------------------
#pragma unroll 1
    for (int pass = 0; pass < 2; ++pass) {
        loadm(GML, pass, m);
        gate2<3, 2>(m, sA, sB); gate2<1, 0>(m, sA, sB); gate2<2, 1>(m, sA, sB); // (0,1)(2,3)(1,2)
        transition2<WA, LA, WB, LB>(slA, slB, c, sA, sB);
        gate2<3, 2>(m, sA, sB); gate2<1, 0>(m, sA, sB); gate2<2, 1>(m, sA, sB); // (4,5)(6,7)(5,6)
        transition2<WB, LB, WC, LC>(slA, slB, c, sA, sB);
        gate2<2, 1>(m, sA, sB); gate2<0, 3>(m, sA, sB);                         // (3,4)(7,0)
        if (pass == 0) transition2<WC, LC, WA, LA>(slA, slB, c, sA, sB);
        else           transition2<WC, LC, WD, LD>(slA, slB, c, sA, sB);
    }

    // ---- LAYER2 x2 in window D (no transitions) --------------------------
#pragma unroll 1
    for (int pp = 0; pp < 2; ++pp) {
        loadm(GML, 2 + pp, m);
        gate2<2, 1>(m, sA, sB); gate2<0, 3>(m, sA, sB);                         // (2,4)(6,0)
        gate2<3, 2>(m, sA, sB); gate2<1, 0>(m, sA, sB);                         // (0,2)(4,6)
    }
    // ---- LAYER3 ----------------------------------------------------------
    loadm(GML, 4, m);
    gate2<2, 0>(m, sA, sB);                                                     // (2,6)

    epilogue(sA, c, bA, out);
    epilogue(sB, c, bB, out);
}

extern "C" void kernel_launch(void* const* d_in, const int* in_sizes, int n_in,
                              void* d_out, int out_size, void* d_ws, size_t ws_size,
                              hipStream_t stream) {
    const float* x = (const float*)d_in[0];
    const float* w = (const float*)d_in[1];
    float* out = (float*)d_out;

    const int batch = in_sizes[0] / 256;   // 8192
    const int nblocks = batch / 8;         // 8 states per 64-thread block
    hipLaunchKernelGGL(sim_kernel, dim3(nblocks), dim3(64), 0, stream, x, w, out);
}